// Round 8
// baseline (177.919 us; speedup 1.0000x reference)
//
#include <hip/hip_runtime.h>
#include <stdint.h>

#define B_SZ 2
#define T_SZ 2048
#define C_SZ 1024
#define NH   16
#define NKV  4
#define HD   64
#define KVD  256
#define QKV_N 1536

typedef __attribute__((ext_vector_type(8))) short bf16x8;
typedef __attribute__((ext_vector_type(4))) float f32x4;

#define GL(p) ((const __attribute__((address_space(1))) void*)(p))
#define LD(p) ((__attribute__((address_space(3))) void*)(p))

__device__ inline unsigned short f2bf(float f) {
  union { float f; unsigned u; } v; v.f = f;
  unsigned u = v.u;
  unsigned r = (u + 0x7fffu + ((u >> 16) & 1u)) >> 16;
  return (unsigned short)r;
}
__device__ inline unsigned short bftrunc(float f) {  // truncate: 1 inst; bias cancels in O/l
  union { float f; unsigned u; } v; v.f = f;
  return (unsigned short)(v.u >> 16);
}

// ---------------- fused fp32->bf16 convert (5 segments) + gate precompute, 1 launch ----------------
struct CvtArgs {
  const float *s0, *s1, *s2, *s3, *s4;
  unsigned short *d0, *d1, *d2, *d3, *d4;
  const float *x, *Wg;
  float *gate;           // [B*T][NKV]
};
__global__ __launch_bounds__(256) void cvt_all(CvtArgs a) {
  int blk = blockIdx.x, tid = threadIdx.x;
  if (blk >= 6656) {  // gate: 3*sigmoid(x[:, :12] @ Wg^T)
    int idx = (blk - 6656) * 256 + tid;
    int bt = idx >> 2, kh = idx & 3;
    float s = 0.f;
#pragma unroll
    for (int j = 0; j < 12; j++) s += a.x[(size_t)bt * C_SZ + j] * a.Wg[kh * 12 + j];
    a.gate[idx] = 3.f / (1.f + __expf(-s));
    return;
  }
  const float* s; unsigned short* d; int i;
  if      (blk < 4096) { s = a.s0; d = a.d0; i = blk * 256 + tid; }
  else if (blk < 5120) { s = a.s1; d = a.d1; i = (blk - 4096) * 256 + tid; }
  else if (blk < 5376) { s = a.s2; d = a.d2; i = (blk - 5120) * 256 + tid; }
  else if (blk < 5632) { s = a.s3; d = a.d3; i = (blk - 5376) * 256 + tid; }
  else                 { s = a.s4; d = a.d4; i = (blk - 5632) * 256 + tid; }
  float4 f = ((const float4*)s)[i];
  ushort4 o;
  o.x = f2bf(f.x); o.y = f2bf(f.y); o.z = f2bf(f.z); o.w = f2bf(f.w);
  ((ushort4*)d)[i] = o;
}

// ========== GEMM core: BM=64 x BN=128, BK=128 as four 32-panels (round-7 config) ==========
#define GEMM_PROLOG(A, Bm, K)                                                        \
  __shared__ unsigned short As[4][64 * 32];                                          \
  __shared__ unsigned short Bs[4][128 * 32];                                         \
  int tid  = threadIdx.x;                                                            \
  int lane = tid & 63;                                                               \
  int wave = tid >> 6;                                                               \
  int quad = lane >> 4;                                                              \
  int l16  = lane & 15;                                                              \
  int m0 = blockIdx.y * 64;                                                          \
  int n0 = blockIdx.x * 128;                                                         \
  int wm = (wave & 1) * 32;                                                          \
  int wn = (wave >> 1) * 64;                                                         \
  f32x4 acc[2][4];                                                                   \
  _Pragma("unroll") for (int i = 0; i < 2; i++)                                      \
    _Pragma("unroll") for (int j = 0; j < 4; j++)                                    \
      acc[i][j] = (f32x4){0.f, 0.f, 0.f, 0.f};                                       \
  int lrow = lane >> 2;                                                              \
  int lcol = (lane & 3) * 8;                                                         \
  int srowA = wave * 16;                                                             \
  int srowB = wave * 32;                                                             \
  const unsigned short* aP  = &A[(size_t)(m0 + srowA + lrow) * K + lcol];            \
  const unsigned short* b0P = &Bm[(size_t)(n0 + srowB + lrow) * K + lcol];           \
  const unsigned short* b1P = b0P + 16 * (size_t)K;                                  \
  for (int k0 = 0; k0 < K; k0 += 128) {                                              \
    __syncthreads();                                                                 \
    _Pragma("unroll") for (int p = 0; p < 4; p++) {                                  \
      __builtin_amdgcn_global_load_lds(GL(aP  + k0 + p * 32), LD(&As[p][srowA * 32]),        16, 0, 0); \
      __builtin_amdgcn_global_load_lds(GL(b0P + k0 + p * 32), LD(&Bs[p][srowB * 32]),        16, 0, 0); \
      __builtin_amdgcn_global_load_lds(GL(b1P + k0 + p * 32), LD(&Bs[p][(srowB + 16) * 32]), 16, 0, 0); \
    }                                                                                \
    __syncthreads();                                                                 \
    _Pragma("unroll") for (int p = 0; p < 4; p++) {                                  \
      bf16x8 af[2], bfr[4];                                                          \
      _Pragma("unroll") for (int i = 0; i < 2; i++)                                  \
        af[i] = *(const bf16x8*)&As[p][(wm + i * 16 + l16) * 32 + quad * 8];         \
      _Pragma("unroll") for (int j = 0; j < 4; j++)                                  \
        bfr[j] = *(const bf16x8*)&Bs[p][(wn + j * 16 + l16) * 32 + quad * 8];        \
      _Pragma("unroll") for (int i = 0; i < 2; i++)                                  \
        _Pragma("unroll") for (int j = 0; j < 4; j++)                                \
          acc[i][j] = __builtin_amdgcn_mfma_f32_16x16x32_bf16(af[i], bfr[j], acc[i][j], 0, 0, 0); \
    }                                                                                \
  }

// ---------------- gemm2: C[m,n] = sum_k A[m,k]*B[n,k], fp32 out ----------------
__global__ __launch_bounds__(256) void gemm_bt(const unsigned short* __restrict__ A,
                                               const unsigned short* __restrict__ Bm,
                                               float* __restrict__ C,
                                               int N, int K) {
  GEMM_PROLOG(A, Bm, K)
#pragma unroll
  for (int i = 0; i < 2; i++) {
#pragma unroll
    for (int j = 0; j < 4; j++) {
      int col = n0 + wn + j * 16 + l16;
#pragma unroll
      for (int r = 0; r < 4; r++) {
        int row = m0 + wm + i * 16 + quad * 4 + r;
        C[(size_t)row * N + col] = acc[i][j][r];
      }
    }
  }
}

// ---------------- gemm1 fused: qkv proj + RoPE + RMSNorm + gate*ve, bf16 out ----------------
__global__ __launch_bounds__(256) void gemm_qkv(const unsigned short* __restrict__ A,
                                                const unsigned short* __restrict__ Bm,
                                                const float* __restrict__ ve,
                                                const float* __restrict__ cosb,
                                                const float* __restrict__ sinb,
                                                const float* __restrict__ gateArr,
                                                unsigned short* __restrict__ qa,
                                                unsigned short* __restrict__ ka,
                                                unsigned short* __restrict__ vt) {
  const int K = C_SZ;
  GEMM_PROLOG(A, Bm, K)

  int colbase = n0 + wn;   // multiple of 64
  if (colbase < 1280) {    // Q or K head
    int isQ = colbase < 1024;
    int h   = isQ ? (colbase >> 6) : ((colbase - 1024) >> 6);
    float scale = isQ ? (0.15f * 1.44269504088896f) : 1.2f;
    unsigned short* dst = isQ ? qa : ka;
    int nheads = isQ ? NH : NKV;
#pragma unroll
    for (int i = 0; i < 2; i++) {
#pragma unroll
      for (int r = 0; r < 4; r++) {
        int row = m0 + wm + i * 16 + quad * 4 + r;   // bt
        int t = row & (T_SZ - 1), b = row >> 11;
        float a10 = acc[i][0][r], a11 = acc[i][1][r];
        float a20 = acc[i][2][r], a21 = acc[i][3][r];
        float cv0 = cosb[t * 32 + l16],      sv0 = sinb[t * 32 + l16];
        float cv1 = cosb[t * 32 + 16 + l16], sv1 = sinb[t * 32 + 16 + l16];
        float o10 =  a10 * cv0 + a20 * sv0;
        float o11 =  a11 * cv1 + a21 * sv1;
        float o20 = -a10 * sv0 + a20 * cv0;
        float o21 = -a11 * sv1 + a21 * cv1;
        float ssq = o10 * o10 + o11 * o11 + o20 * o20 + o21 * o21;
        ssq += __shfl_xor(ssq, 1);
        ssq += __shfl_xor(ssq, 2);
        ssq += __shfl_xor(ssq, 4);
        ssq += __shfl_xor(ssq, 8);
        float rn = rsqrtf(ssq * (1.f / 64.f) + 1e-6f) * scale;
        size_t base = ((size_t)(b * nheads + h) * T_SZ + t) * HD;
        dst[base + l16]      = f2bf(o10 * rn);
        dst[base + 16 + l16] = f2bf(o11 * rn);
        dst[base + 32 + l16] = f2bf(o20 * rn);
        dst[base + 48 + l16] = f2bf(o21 * rn);
      }
    }
  } else {                 // V head: add gate*ve, write transposed
    int kh = (colbase - 1280) >> 6;
#pragma unroll
    for (int i = 0; i < 2; i++) {
#pragma unroll
      for (int r = 0; r < 4; r++) {
        int row = m0 + wm + i * 16 + quad * 4 + r;   // bt
        int t = row & (T_SZ - 1), b = row >> 11;
        float g = gateArr[row * 4 + kh];
        size_t vbase = ((size_t)(b * NKV + kh) * HD) * T_SZ;
#pragma unroll
        for (int j = 0; j < 4; j++) {
          int d = j * 16 + l16;
          float val = acc[i][j][r] + g * ve[(size_t)row * KVD + kh * HD + d];
          vt[vbase + (size_t)d * T_SZ + t] = f2bf(val);
        }
      }
    }
  }
}

// ---------------- causal flash attention: Q=128, S^T trick, split-K for heavy tiles ----------------
// No-max softmax (scores bounded by RMSNorm) makes partials ADDITIVE: O_unnorm and l just
// sum across disjoint t-ranges. qt>=8 tiles split into two equal halves (<=16 iters);
// 24 equal-ish work units per bh, heavy-first static order -> 768 blocks, ~3/CU backlog.
// Split units write f32 partials (O,l) to pbuf; attn_merge sums+normalizes.
#define KST 72
#define PST 72
#define PUNIT 8320   // floats per partial: 128*64 O + 128 l
__global__ __launch_bounds__(256) void attn(const unsigned short* __restrict__ qa,
                                            const unsigned short* __restrict__ ka,
                                            const unsigned short* __restrict__ vt,
                                            unsigned short* __restrict__ y,
                                            float* __restrict__ pbuf) {
  // heavy-first unit table (work = j1-j0 descending)
  const int U_QT[24] = {15,15,7,14,14,6,13,13,12,12,5,11,11,10,10,4,9,9,8,8,3,2,1,0};
  const int U_J0[24] = {0,16,0,0,15,0,0,14,0,13,0,0,12,0,11,0,0,10,0,9,0,0,0,0};
  const int U_J1[24] = {16,32,16,15,30,14,14,28,13,26,12,12,24,11,22,10,10,20,9,18,8,6,4,2};

  int bid = blockIdx.x;
  int u = bid >> 5, bh = bid & 31;
  int qt = U_QT[u], j0 = U_J0[u], j1 = U_J1[u];
  int split = (qt >= 8);
  int part = (j0 != 0) ? 1 : 0;
  int b = bh >> 4, h = bh & 15;
  int kh = h >> 2;
  int tid = threadIdx.x;
  int wave = tid >> 6, lane = tid & 63;
  int quad = lane >> 4, l16 = lane & 15;

  __shared__ unsigned short Ks[64 * KST];    // [t_local][d]
  __shared__ unsigned short Vs[64 * KST];    // [d][t_local]
  __shared__ unsigned short Ps[128 * PST];   // [q_local][t_local]
  unsigned short* Pw = &Ps[(wave * 32) * PST];

  // Q fragments (B operand): lane l16 = q within block, quad*8+j = d
  bf16x8 bq[2][2];
#pragma unroll
  for (int qi = 0; qi < 2; qi++) {
    int tq = qt * 128 + wave * 32 + qi * 16 + l16;
    const unsigned short* qp = &qa[((size_t)(b * NH + h) * T_SZ + tq) * HD];
    bq[qi][0] = *(const bf16x8*)&qp[quad * 8];
    bq[qi][1] = *(const bf16x8*)&qp[32 + quad * 8];
  }

  const unsigned short one_bf = 0x3F80;
  bf16x8 vones = {(short)one_bf, (short)one_bf, (short)one_bf, (short)one_bf,
                  (short)one_bf, (short)one_bf, (short)one_bf, (short)one_bf};

  f32x4 oacc[2][4];
  f32x4 lacc[2];
#pragma unroll
  for (int qi = 0; qi < 2; qi++) {
    lacc[qi] = (f32x4){0.f, 0.f, 0.f, 0.f};
#pragma unroll
    for (int d = 0; d < 4; d++) oacc[qi][d] = (f32x4){0.f, 0.f, 0.f, 0.f};
  }

  int lr = tid >> 2;          // 0..63
  int lc = (tid & 3) * 16;    // 0,16,32,48

  const unsigned short* kbase = &ka[(size_t)(b * NKV + kh) * T_SZ * HD];
  const unsigned short* vbase = &vt[(size_t)(b * NKV + kh) * HD * T_SZ];

  uint4 k0, k1, v0, v1;
  {
    const unsigned short* kp = &kbase[(size_t)(j0 * 64 + lr) * HD + lc];
    const unsigned short* vp = &vbase[(size_t)lr * T_SZ + j0 * 64 + lc];
    k0 = *(const uint4*)(kp);
    k1 = *(const uint4*)(kp + 8);
    v0 = *(const uint4*)(vp);
    v1 = *(const uint4*)(vp + 8);
  }

  int qrow0 = qt * 128 + wave * 32;

  for (int j = j0; j < j1; j++) {
    __syncthreads();
    *(uint4*)&Ks[lr * KST + lc]     = k0;
    *(uint4*)&Ks[lr * KST + lc + 8] = k1;
    *(uint4*)&Vs[lr * KST + lc]     = v0;
    *(uint4*)&Vs[lr * KST + lc + 8] = v1;
    __syncthreads();

    if (j + 1 < j1) {  // issue next tile's loads now; they fly through this tile's compute
      const unsigned short* kp = &kbase[(size_t)((j + 1) * 64 + lr) * HD + lc];
      const unsigned short* vp = &vbase[(size_t)lr * T_SZ + (j + 1) * 64 + lc];
      k0 = *(const uint4*)(kp);
      k1 = *(const uint4*)(kp + 8);
      v0 = *(const uint4*)(vp);
      v1 = *(const uint4*)(vp + 8);
    }

    // S^T = K Q^T: D[m=t][n=q]; K-frags as A shared across both q-blocks
    f32x4 st[4][2];
#pragma unroll
    for (int tb = 0; tb < 4; tb++) {
      bf16x8 ak0 = *(const bf16x8*)&Ks[(tb * 16 + l16) * KST + quad * 8];
      bf16x8 ak1 = *(const bf16x8*)&Ks[(tb * 16 + l16) * KST + 32 + quad * 8];
#pragma unroll
      for (int qi = 0; qi < 2; qi++) {
        f32x4 s = (f32x4){0.f, 0.f, 0.f, 0.f};
        s = __builtin_amdgcn_mfma_f32_16x16x32_bf16(ak0, bq[qi][0], s, 0, 0, 0);
        s = __builtin_amdgcn_mfma_f32_16x16x32_bf16(ak1, bq[qi][1], s, 0, 0, 0);
        st[tb][qi] = s;
      }
    }

    // mask + exp2 + packed b64 store of P[q][t] (per-wave region, no barrier needed)
#pragma unroll
    for (int qi = 0; qi < 2; qi++) {
      int qlow = qrow0 + qi * 16;          // this block's q = qlow + l16
      if (j * 64 + 63 > qlow) {            // near-diagonal tiles only
        int qg = qlow + l16;
#pragma unroll
        for (int tb = 0; tb < 4; tb++) {
          int tg = j * 64 + tb * 16 + quad * 4;
#pragma unroll
          for (int i = 0; i < 4; i++) {
            if (tg + i > qg) st[tb][qi][i] = -__builtin_inff();
          }
        }
      }
#pragma unroll
      for (int tb = 0; tb < 4; tb++) {
        ushort4 w;
        w.x = bftrunc(__builtin_amdgcn_exp2f(st[tb][qi][0]));
        w.y = bftrunc(__builtin_amdgcn_exp2f(st[tb][qi][1]));
        w.z = bftrunc(__builtin_amdgcn_exp2f(st[tb][qi][2]));
        w.w = bftrunc(__builtin_amdgcn_exp2f(st[tb][qi][3]));
        *(ushort4*)&Pw[(qi * 16 + l16) * PST + tb * 16 + quad * 4] = w;
      }
    }

    bf16x8 ap[2][2];
#pragma unroll
    for (int qi = 0; qi < 2; qi++) {
      ap[qi][0] = *(const bf16x8*)&Pw[(qi * 16 + l16) * PST + quad * 8];
      ap[qi][1] = *(const bf16x8*)&Pw[(qi * 16 + l16) * PST + 32 + quad * 8];
      lacc[qi] = __builtin_amdgcn_mfma_f32_16x16x32_bf16(ap[qi][0], vones, lacc[qi], 0, 0, 0);
      lacc[qi] = __builtin_amdgcn_mfma_f32_16x16x32_bf16(ap[qi][1], vones, lacc[qi], 0, 0, 0);
    }
#pragma unroll
    for (int d = 0; d < 4; d++) {
      bf16x8 bv0 = *(const bf16x8*)&Vs[(d * 16 + l16) * KST + quad * 8];
      bf16x8 bv1 = *(const bf16x8*)&Vs[(d * 16 + l16) * KST + 32 + quad * 8];
#pragma unroll
      for (int qi = 0; qi < 2; qi++) {
        oacc[qi][d] = __builtin_amdgcn_mfma_f32_16x16x32_bf16(ap[qi][0], bv0, oacc[qi][d], 0, 0, 0);
        oacc[qi][d] = __builtin_amdgcn_mfma_f32_16x16x32_bf16(ap[qi][1], bv1, oacc[qi][d], 0, 0, 0);
      }
    }
  }

  if (split) {
    // write f32 partials: O rows [0,128) x cols [0,64), then l per row
    float* pb = &pbuf[(size_t)(((bh * 8 + (qt - 8)) * 2 + part)) * PUNIT];
#pragma unroll
    for (int qi = 0; qi < 2; qi++) {
#pragma unroll
      for (int i = 0; i < 4; i++) {
        int row = wave * 32 + qi * 16 + quad * 4 + i;
#pragma unroll
        for (int d = 0; d < 4; d++)
          pb[row * 64 + d * 16 + l16] = oacc[qi][d][i];
        if (l16 == 0) pb[8192 + row] = lacc[qi][i];
      }
    }
  } else {
#pragma unroll
    for (int qi = 0; qi < 2; qi++) {
#pragma unroll
      for (int i = 0; i < 4; i++) {
        int tq = qrow0 + qi * 16 + quad * 4 + i;
        float inv = 1.f / lacc[qi][i];
#pragma unroll
        for (int d = 0; d < 4; d++) {
          y[((size_t)(b * T_SZ) + tq) * C_SZ + h * HD + d * 16 + l16] = f2bf(oacc[qi][d][i] * inv);
        }
      }
    }
  }
}

// ---------------- merge split partials: y = (O0+O1)/(l0+l1) ----------------
__global__ __launch_bounds__(256) void attn_merge(const float* __restrict__ pbuf,
                                                  unsigned short* __restrict__ y) {
  int unit = blockIdx.x;          // bh*8 + (qt-8)
  int bh = unit >> 3, qt = (unit & 7) + 8;
  int b = bh >> 4, h = bh & 15;
  const float* p0 = &pbuf[(size_t)(unit * 2) * PUNIT];
  const float* p1 = p0 + PUNIT;
  int d = threadIdx.x & 63;
  int r0 = (threadIdx.x >> 6) * 32;
#pragma unroll 4
  for (int r = r0; r < r0 + 32; r++) {
    float l = p0[8192 + r] + p1[8192 + r];
    float o = p0[r * 64 + d] + p1[r * 64 + d];
    int t = qt * 128 + r;
    y[((size_t)(b * T_SZ) + t) * C_SZ + h * HD + d] = f2bf(o * (1.f / l));
  }
}

extern "C" void kernel_launch(void* const* d_in, const int* in_sizes, int n_in,
                              void* d_out, int out_size, void* d_ws, size_t ws_size,
                              hipStream_t stream) {
  const float* x    = (const float*)d_in[0];
  const float* ve   = (const float*)d_in[1];
  const float* cosb = (const float*)d_in[2];
  const float* sinb = (const float*)d_in[3];
  const float* Wq   = (const float*)d_in[4];
  const float* Wk   = (const float*)d_in[5];
  const float* Wv   = (const float*)d_in[6];
  const float* Wo   = (const float*)d_in[7];
  const float* Wg   = (const float*)d_in[8];
  float* out = (float*)d_out;

  const size_t MB = 1024 * 1024;
  char* ws = (char*)d_ws;
  unsigned short* xb    = (unsigned short*)(ws);             // 8 MB (reused as yb)
  unsigned short* wqkvb = (unsigned short*)(ws + 8 * MB);    // 3 MB
  unsigned short* wob   = (unsigned short*)(ws + 11 * MB);   // 2 MB
  unsigned short* qab   = (unsigned short*)(ws + 13 * MB);   // 8 MB
  unsigned short* kab   = (unsigned short*)(ws + 21 * MB);   // 2 MB
  unsigned short* vtb   = (unsigned short*)(ws + 23 * MB);   // 2 MB
  float*          gateA = (float*)(ws + 25 * MB);            // 64 KB
  float*          pbuf  = (float*)(ws + 26 * MB);            // 512*8320*4 B ~ 17 MB
  unsigned short* yb    = xb;                                // reuse after gemm_qkv

  CvtArgs ca;
  ca.s0 = x;  ca.d0 = xb;
  ca.s1 = Wq; ca.d1 = wqkvb;
  ca.s2 = Wk; ca.d2 = wqkvb + 1024 * 1024;
  ca.s3 = Wv; ca.d3 = wqkvb + 1280 * 1024;
  ca.s4 = Wo; ca.d4 = wob;
  ca.x = x; ca.Wg = Wg; ca.gate = gateA;
  cvt_all<<<6720, 256, 0, stream>>>(ca);

  gemm_qkv<<<dim3(QKV_N / 128, (B_SZ * T_SZ) / 64), 256, 0, stream>>>(
      xb, wqkvb, ve, cosb, sinb, gateA, qab, kab, vtb);

  attn<<<768, 256, 0, stream>>>(qab, kab, vtb, yb, pbuf);

  attn_merge<<<256, 256, 0, stream>>>(pbuf, yb);

  gemm_bt<<<dim3(C_SZ / 128, (B_SZ * T_SZ) / 64), 256, 0, stream>>>(
      yb, wob, out, C_SZ, C_SZ);
}

// Round 9
// 172.656 us; speedup vs baseline: 1.0305x; 1.0305x over previous
//
#include <hip/hip_runtime.h>
#include <stdint.h>

#define B_SZ 2
#define T_SZ 2048
#define C_SZ 1024
#define NH   16
#define NKV  4
#define HD   64
#define KVD  256
#define QKV_N 1536

typedef __attribute__((ext_vector_type(8))) short bf16x8;
typedef __attribute__((ext_vector_type(4))) float f32x4;

#define GL(p) ((const __attribute__((address_space(1))) void*)(p))
#define LD(p) ((__attribute__((address_space(3))) void*)(p))

__device__ inline unsigned short f2bf(float f) {
  union { float f; unsigned u; } v; v.f = f;
  unsigned u = v.u;
  unsigned r = (u + 0x7fffu + ((u >> 16) & 1u)) >> 16;
  return (unsigned short)r;
}
__device__ inline unsigned short bftrunc(float f) {  // truncate: 1 inst; bias cancels in O/l
  union { float f; unsigned u; } v; v.f = f;
  return (unsigned short)(v.u >> 16);
}

// ---------------- fused fp32->bf16 convert (5 segments) + gate precompute, 1 launch ----------------
struct CvtArgs {
  const float *s0, *s1, *s2, *s3, *s4;
  unsigned short *d0, *d1, *d2, *d3, *d4;
  const float *x, *Wg;
  float *gate;           // [B*T][NKV]
};
__global__ __launch_bounds__(256) void cvt_all(CvtArgs a) {
  int blk = blockIdx.x, tid = threadIdx.x;
  if (blk >= 6656) {  // gate: 3*sigmoid(x[:, :12] @ Wg^T)
    int idx = (blk - 6656) * 256 + tid;
    int bt = idx >> 2, kh = idx & 3;
    float s = 0.f;
#pragma unroll
    for (int j = 0; j < 12; j++) s += a.x[(size_t)bt * C_SZ + j] * a.Wg[kh * 12 + j];
    a.gate[idx] = 3.f / (1.f + __expf(-s));
    return;
  }
  const float* s; unsigned short* d; int i;
  if      (blk < 4096) { s = a.s0; d = a.d0; i = blk * 256 + tid; }
  else if (blk < 5120) { s = a.s1; d = a.d1; i = (blk - 4096) * 256 + tid; }
  else if (blk < 5376) { s = a.s2; d = a.d2; i = (blk - 5120) * 256 + tid; }
  else if (blk < 5632) { s = a.s3; d = a.d3; i = (blk - 5376) * 256 + tid; }
  else                 { s = a.s4; d = a.d4; i = (blk - 5632) * 256 + tid; }
  float4 f = ((const float4*)s)[i];
  ushort4 o;
  o.x = f2bf(f.x); o.y = f2bf(f.y); o.z = f2bf(f.z); o.w = f2bf(f.w);
  ((ushort4*)d)[i] = o;
}

// ========== GEMM core: BM=64 x BN=128, BK=128 as four 32-panels (round-7 config) ==========
#define GEMM_PROLOG(A, Bm, K)                                                        \
  __shared__ unsigned short As[4][64 * 32];                                          \
  __shared__ unsigned short Bs[4][128 * 32];                                         \
  int tid  = threadIdx.x;                                                            \
  int lane = tid & 63;                                                               \
  int wave = tid >> 6;                                                               \
  int quad = lane >> 4;                                                              \
  int l16  = lane & 15;                                                              \
  int m0 = blockIdx.y * 64;                                                          \
  int n0 = blockIdx.x * 128;                                                         \
  int wm = (wave & 1) * 32;                                                          \
  int wn = (wave >> 1) * 64;                                                         \
  f32x4 acc[2][4];                                                                   \
  _Pragma("unroll") for (int i = 0; i < 2; i++)                                      \
    _Pragma("unroll") for (int j = 0; j < 4; j++)                                    \
      acc[i][j] = (f32x4){0.f, 0.f, 0.f, 0.f};                                       \
  int lrow = lane >> 2;                                                              \
  int lcol = (lane & 3) * 8;                                                         \
  int srowA = wave * 16;                                                             \
  int srowB = wave * 32;                                                             \
  const unsigned short* aP  = &A[(size_t)(m0 + srowA + lrow) * K + lcol];            \
  const unsigned short* b0P = &Bm[(size_t)(n0 + srowB + lrow) * K + lcol];           \
  const unsigned short* b1P = b0P + 16 * (size_t)K;                                  \
  for (int k0 = 0; k0 < K; k0 += 128) {                                              \
    __syncthreads();                                                                 \
    _Pragma("unroll") for (int p = 0; p < 4; p++) {                                  \
      __builtin_amdgcn_global_load_lds(GL(aP  + k0 + p * 32), LD(&As[p][srowA * 32]),        16, 0, 0); \
      __builtin_amdgcn_global_load_lds(GL(b0P + k0 + p * 32), LD(&Bs[p][srowB * 32]),        16, 0, 0); \
      __builtin_amdgcn_global_load_lds(GL(b1P + k0 + p * 32), LD(&Bs[p][(srowB + 16) * 32]), 16, 0, 0); \
    }                                                                                \
    __syncthreads();                                                                 \
    _Pragma("unroll") for (int p = 0; p < 4; p++) {                                  \
      bf16x8 af[2], bfr[4];                                                          \
      _Pragma("unroll") for (int i = 0; i < 2; i++)                                  \
        af[i] = *(const bf16x8*)&As[p][(wm + i * 16 + l16) * 32 + quad * 8];         \
      _Pragma("unroll") for (int j = 0; j < 4; j++)                                  \
        bfr[j] = *(const bf16x8*)&Bs[p][(wn + j * 16 + l16) * 32 + quad * 8];        \
      _Pragma("unroll") for (int i = 0; i < 2; i++)                                  \
        _Pragma("unroll") for (int j = 0; j < 4; j++)                                \
          acc[i][j] = __builtin_amdgcn_mfma_f32_16x16x32_bf16(af[i], bfr[j], acc[i][j], 0, 0, 0); \
    }                                                                                \
  }

// ---------------- gemm2: C[m,n] = sum_k A[m,k]*B[n,k], fp32 out ----------------
__global__ __launch_bounds__(256) void gemm_bt(const unsigned short* __restrict__ A,
                                               const unsigned short* __restrict__ Bm,
                                               float* __restrict__ C,
                                               int N, int K) {
  GEMM_PROLOG(A, Bm, K)
#pragma unroll
  for (int i = 0; i < 2; i++) {
#pragma unroll
    for (int j = 0; j < 4; j++) {
      int col = n0 + wn + j * 16 + l16;
#pragma unroll
      for (int r = 0; r < 4; r++) {
        int row = m0 + wm + i * 16 + quad * 4 + r;
        C[(size_t)row * N + col] = acc[i][j][r];
      }
    }
  }
}

// ---------------- gemm1 fused: qkv proj + RoPE + RMSNorm + gate*ve, bf16 out ----------------
// V now written COALESCED row-major (bt, kh*64+d); v_transpose produces (B,NKV,HD,T).
__global__ __launch_bounds__(256) void gemm_qkv(const unsigned short* __restrict__ A,
                                                const unsigned short* __restrict__ Bm,
                                                const float* __restrict__ ve,
                                                const float* __restrict__ cosb,
                                                const float* __restrict__ sinb,
                                                const float* __restrict__ gateArr,
                                                unsigned short* __restrict__ qa,
                                                unsigned short* __restrict__ ka,
                                                unsigned short* __restrict__ vtmp) {
  const int K = C_SZ;
  GEMM_PROLOG(A, Bm, K)

  int colbase = n0 + wn;   // multiple of 64
  if (colbase < 1280) {    // Q or K head
    int isQ = colbase < 1024;
    int h   = isQ ? (colbase >> 6) : ((colbase - 1024) >> 6);
    float scale = isQ ? (0.15f * 1.44269504088896f) : 1.2f;
    unsigned short* dst = isQ ? qa : ka;
    int nheads = isQ ? NH : NKV;
#pragma unroll
    for (int i = 0; i < 2; i++) {
#pragma unroll
      for (int r = 0; r < 4; r++) {
        int row = m0 + wm + i * 16 + quad * 4 + r;   // bt
        int t = row & (T_SZ - 1), b = row >> 11;
        float a10 = acc[i][0][r], a11 = acc[i][1][r];
        float a20 = acc[i][2][r], a21 = acc[i][3][r];
        float cv0 = cosb[t * 32 + l16],      sv0 = sinb[t * 32 + l16];
        float cv1 = cosb[t * 32 + 16 + l16], sv1 = sinb[t * 32 + 16 + l16];
        float o10 =  a10 * cv0 + a20 * sv0;
        float o11 =  a11 * cv1 + a21 * sv1;
        float o20 = -a10 * sv0 + a20 * cv0;
        float o21 = -a11 * sv1 + a21 * cv1;
        float ssq = o10 * o10 + o11 * o11 + o20 * o20 + o21 * o21;
        ssq += __shfl_xor(ssq, 1);
        ssq += __shfl_xor(ssq, 2);
        ssq += __shfl_xor(ssq, 4);
        ssq += __shfl_xor(ssq, 8);
        float rn = rsqrtf(ssq * (1.f / 64.f) + 1e-6f) * scale;
        size_t base = ((size_t)(b * nheads + h) * T_SZ + t) * HD;
        dst[base + l16]      = f2bf(o10 * rn);
        dst[base + 16 + l16] = f2bf(o11 * rn);
        dst[base + 32 + l16] = f2bf(o20 * rn);
        dst[base + 48 + l16] = f2bf(o21 * rn);
      }
    }
  } else {                 // V head: add gate*ve, write coalesced (bt, kh*64+d)
    int kh = (colbase - 1280) >> 6;
#pragma unroll
    for (int i = 0; i < 2; i++) {
#pragma unroll
      for (int r = 0; r < 4; r++) {
        int row = m0 + wm + i * 16 + quad * 4 + r;   // bt
        float g = gateArr[row * 4 + kh];
#pragma unroll
        for (int j = 0; j < 4; j++) {
          int d = j * 16 + l16;
          float val = acc[i][j][r] + g * ve[(size_t)row * KVD + kh * HD + d];
          vtmp[(size_t)row * KVD + kh * HD + d] = f2bf(val);
        }
      }
    }
  }
}

// ---------------- V transpose: (B*T, NKV*HD) -> (B,NKV,HD,T), 64x64 LDS tiles ----------------
// LDS stride 68 shorts (136 B): column reads are 2-way bank aliased = free (m136).
__global__ __launch_bounds__(256) void v_transpose(const unsigned short* __restrict__ vtmp,
                                                   unsigned short* __restrict__ vt) {
  __shared__ unsigned short tile[64 * 68];
  int blk = blockIdx.x;               // b(2) x kh(4) x tb(32)
  int tb = blk & 31, kh = (blk >> 5) & 3, b = blk >> 7;
  int tid = threadIdx.x;
  // load 64 t-rows x 64 d-cols: each thread 2 x uint4 (8 shorts)
  int r = tid >> 2, c = (tid & 3) * 16;   // rows 0..63, col-chunks of 16
  const unsigned short* src = &vtmp[((size_t)(b * T_SZ + tb * 64 + r)) * KVD + kh * HD + c];
  uint4 x0 = *(const uint4*)(src);
  uint4 x1 = *(const uint4*)(src + 8);
  *(uint2*)&tile[r * 68 + c]      = *(uint2*)&x0;
  *(uint2*)&tile[r * 68 + c + 4]  = *((uint2*)&x0 + 1);
  *(uint2*)&tile[r * 68 + c + 8]  = *(uint2*)&x1;
  *(uint2*)&tile[r * 68 + c + 12] = *((uint2*)&x1 + 1);
  __syncthreads();
  // write out: row d = tid>>2 (0..63), t-chunk (tid&3)*16
  int d = tid >> 2, tc = (tid & 3) * 16;
  ushort4 o0, o1, o2, o3;
  o0.x = tile[(tc + 0) * 68 + d];  o0.y = tile[(tc + 1) * 68 + d];
  o0.z = tile[(tc + 2) * 68 + d];  o0.w = tile[(tc + 3) * 68 + d];
  o1.x = tile[(tc + 4) * 68 + d];  o1.y = tile[(tc + 5) * 68 + d];
  o1.z = tile[(tc + 6) * 68 + d];  o1.w = tile[(tc + 7) * 68 + d];
  o2.x = tile[(tc + 8) * 68 + d];  o2.y = tile[(tc + 9) * 68 + d];
  o2.z = tile[(tc + 10) * 68 + d]; o2.w = tile[(tc + 11) * 68 + d];
  o3.x = tile[(tc + 12) * 68 + d]; o3.y = tile[(tc + 13) * 68 + d];
  o3.z = tile[(tc + 14) * 68 + d]; o3.w = tile[(tc + 15) * 68 + d];
  unsigned short* dst = &vt[((size_t)(b * NKV + kh) * HD + d) * T_SZ + tb * 64 + tc];
  *(ushort4*)(dst)      = o0;
  *(ushort4*)(dst + 4)  = o1;
  *(ushort4*)(dst + 8)  = o2;
  *(ushort4*)(dst + 12) = o3;
}

// ---------------- causal flash attention: Q=128, S^T trick, single-barrier dbuf ----------------
// Ping-pong K/V staging: iter j reads buf[j&1], writes next tile to buf[(j+1)&1] ->
// ONE barrier per iteration (the barrier's lgkm drain covers both write-visibility and
// read-completion). Prefetch issued just after the barrier, consumed by the buf-write at
// iter end, so global loads have the whole compute phase in flight.
#define KST 72
#define PST 72
__global__ __launch_bounds__(256) void attn(const unsigned short* __restrict__ qa,
                                            const unsigned short* __restrict__ ka,
                                            const unsigned short* __restrict__ vt,
                                            unsigned short* __restrict__ y) {
  // pair qt with 15-qt so co-resident blocks sum to equal work
  int bid = blockIdx.x;
  int half = bid >> 8, r = bid & 255;
  int qt = half ? (r & 15) : 15 - (r & 15);
  int bh = (half << 4) | (r >> 4);
  int b = bh >> 4, h = bh & 15;
  int kh = h >> 2;
  int tid = threadIdx.x;
  int wave = tid >> 6, lane = tid & 63;
  int quad = lane >> 4, l16 = lane & 15;

  __shared__ unsigned short Ks[2][64 * KST];   // [t_local][d]
  __shared__ unsigned short Vs[2][64 * KST];   // [d][t_local]
  __shared__ unsigned short Ps[128 * PST];     // [q_local][t_local]
  unsigned short* Pw = &Ps[(wave * 32) * PST];

  // Q fragments (B operand): lane l16 = q within block, quad*8+j = d
  bf16x8 bq[2][2];
#pragma unroll
  for (int qi = 0; qi < 2; qi++) {
    int tq = qt * 128 + wave * 32 + qi * 16 + l16;
    const unsigned short* qp = &qa[((size_t)(b * NH + h) * T_SZ + tq) * HD];
    bq[qi][0] = *(const bf16x8*)&qp[quad * 8];
    bq[qi][1] = *(const bf16x8*)&qp[32 + quad * 8];
  }

  const unsigned short one_bf = 0x3F80;
  bf16x8 vones = {(short)one_bf, (short)one_bf, (short)one_bf, (short)one_bf,
                  (short)one_bf, (short)one_bf, (short)one_bf, (short)one_bf};

  f32x4 oacc[2][4];
  f32x4 lacc[2];
#pragma unroll
  for (int qi = 0; qi < 2; qi++) {
    lacc[qi] = (f32x4){0.f, 0.f, 0.f, 0.f};
#pragma unroll
    for (int d = 0; d < 4; d++) oacc[qi][d] = (f32x4){0.f, 0.f, 0.f, 0.f};
  }

  int lr = tid >> 2;          // 0..63
  int lc = (tid & 3) * 16;    // 0,16,32,48

  const unsigned short* kbase = &ka[(size_t)(b * NKV + kh) * T_SZ * HD];
  const unsigned short* vbase = &vt[(size_t)(b * NKV + kh) * HD * T_SZ];

  int nj = 2 * qt + 2;

  // preload tile 0 and stage into buffer 0 (visible after first barrier)
  {
    const unsigned short* kp = &kbase[(size_t)lr * HD + lc];
    const unsigned short* vp = &vbase[(size_t)lr * T_SZ + lc];
    uint4 k0 = *(const uint4*)(kp);
    uint4 k1 = *(const uint4*)(kp + 8);
    uint4 v0 = *(const uint4*)(vp);
    uint4 v1 = *(const uint4*)(vp + 8);
    *(uint4*)&Ks[0][lr * KST + lc]     = k0;
    *(uint4*)&Ks[0][lr * KST + lc + 8] = k1;
    *(uint4*)&Vs[0][lr * KST + lc]     = v0;
    *(uint4*)&Vs[0][lr * KST + lc + 8] = v1;
  }

  int qrow0 = qt * 128 + wave * 32;

  for (int j = 0; j < nj; j++) {
    int cur = j & 1, nxt = cur ^ 1;
    __syncthreads();   // buf[cur] writes visible; all prior reads drained

    uint4 k0, k1, v0, v1;
    bool pf = (j + 1 < nj);
    if (pf) {  // issue next tile's loads; they fly through this tile's compute
      const unsigned short* kp = &kbase[(size_t)((j + 1) * 64 + lr) * HD + lc];
      const unsigned short* vp = &vbase[(size_t)lr * T_SZ + (j + 1) * 64 + lc];
      k0 = *(const uint4*)(kp);
      k1 = *(const uint4*)(kp + 8);
      v0 = *(const uint4*)(vp);
      v1 = *(const uint4*)(vp + 8);
    }

    // S^T = K Q^T: D[m=t][n=q]; K-frags as A shared across both q-blocks
    f32x4 st[4][2];
#pragma unroll
    for (int tb = 0; tb < 4; tb++) {
      bf16x8 ak0 = *(const bf16x8*)&Ks[cur][(tb * 16 + l16) * KST + quad * 8];
      bf16x8 ak1 = *(const bf16x8*)&Ks[cur][(tb * 16 + l16) * KST + 32 + quad * 8];
#pragma unroll
      for (int qi = 0; qi < 2; qi++) {
        f32x4 s = (f32x4){0.f, 0.f, 0.f, 0.f};
        s = __builtin_amdgcn_mfma_f32_16x16x32_bf16(ak0, bq[qi][0], s, 0, 0, 0);
        s = __builtin_amdgcn_mfma_f32_16x16x32_bf16(ak1, bq[qi][1], s, 0, 0, 0);
        st[tb][qi] = s;
      }
    }

    // mask + exp2 + packed b64 store of P[q][t] (per-wave region, no barrier needed)
#pragma unroll
    for (int qi = 0; qi < 2; qi++) {
      int qlow = qrow0 + qi * 16;          // this block's q = qlow + l16
      if (j * 64 + 63 > qlow) {            // near-diagonal tiles only
        int qg = qlow + l16;
#pragma unroll
        for (int tb = 0; tb < 4; tb++) {
          int tg = j * 64 + tb * 16 + quad * 4;
#pragma unroll
          for (int i = 0; i < 4; i++) {
            if (tg + i > qg) st[tb][qi][i] = -__builtin_inff();
          }
        }
      }
#pragma unroll
      for (int tb = 0; tb < 4; tb++) {
        ushort4 w;
        w.x = bftrunc(__builtin_amdgcn_exp2f(st[tb][qi][0]));
        w.y = bftrunc(__builtin_amdgcn_exp2f(st[tb][qi][1]));
        w.z = bftrunc(__builtin_amdgcn_exp2f(st[tb][qi][2]));
        w.w = bftrunc(__builtin_amdgcn_exp2f(st[tb][qi][3]));
        *(ushort4*)&Pw[(qi * 16 + l16) * PST + tb * 16 + quad * 4] = w;
      }
    }

    bf16x8 ap[2][2];
#pragma unroll
    for (int qi = 0; qi < 2; qi++) {
      ap[qi][0] = *(const bf16x8*)&Pw[(qi * 16 + l16) * PST + quad * 8];
      ap[qi][1] = *(const bf16x8*)&Pw[(qi * 16 + l16) * PST + 32 + quad * 8];
      lacc[qi] = __builtin_amdgcn_mfma_f32_16x16x32_bf16(ap[qi][0], vones, lacc[qi], 0, 0, 0);
      lacc[qi] = __builtin_amdgcn_mfma_f32_16x16x32_bf16(ap[qi][1], vones, lacc[qi], 0, 0, 0);
    }
#pragma unroll
    for (int d = 0; d < 4; d++) {
      bf16x8 bv0 = *(const bf16x8*)&Vs[cur][(d * 16 + l16) * KST + quad * 8];
      bf16x8 bv1 = *(const bf16x8*)&Vs[cur][(d * 16 + l16) * KST + 32 + quad * 8];
#pragma unroll
      for (int qi = 0; qi < 2; qi++) {
        oacc[qi][d] = __builtin_amdgcn_mfma_f32_16x16x32_bf16(ap[qi][0], bv0, oacc[qi][d], 0, 0, 0);
        oacc[qi][d] = __builtin_amdgcn_mfma_f32_16x16x32_bf16(ap[qi][1], bv1, oacc[qi][d], 0, 0, 0);
      }
    }

    if (pf) {  // stage next tile into the other buffer (read concurrently-safe: disjoint)
      *(uint4*)&Ks[nxt][lr * KST + lc]     = k0;
      *(uint4*)&Ks[nxt][lr * KST + lc + 8] = k1;
      *(uint4*)&Vs[nxt][lr * KST + lc]     = v0;
      *(uint4*)&Vs[nxt][lr * KST + lc + 8] = v1;
    }
  }

#pragma unroll
  for (int qi = 0; qi < 2; qi++) {
#pragma unroll
    for (int i = 0; i < 4; i++) {
      int tq = qrow0 + qi * 16 + quad * 4 + i;
      float inv = 1.f / lacc[qi][i];
#pragma unroll
      for (int d = 0; d < 4; d++) {
        y[((size_t)(b * T_SZ) + tq) * C_SZ + h * HD + d * 16 + l16] = f2bf(oacc[qi][d][i] * inv);
      }
    }
  }
}

extern "C" void kernel_launch(void* const* d_in, const int* in_sizes, int n_in,
                              void* d_out, int out_size, void* d_ws, size_t ws_size,
                              hipStream_t stream) {
  const float* x    = (const float*)d_in[0];
  const float* ve   = (const float*)d_in[1];
  const float* cosb = (const float*)d_in[2];
  const float* sinb = (const float*)d_in[3];
  const float* Wq   = (const float*)d_in[4];
  const float* Wk   = (const float*)d_in[5];
  const float* Wv   = (const float*)d_in[6];
  const float* Wo   = (const float*)d_in[7];
  const float* Wg   = (const float*)d_in[8];
  float* out = (float*)d_out;

  const size_t MB = 1024 * 1024;
  char* ws = (char*)d_ws;
  unsigned short* xb    = (unsigned short*)(ws);             // 8 MB (reused as yb)
  unsigned short* wqkvb = (unsigned short*)(ws + 8 * MB);    // 3 MB
  unsigned short* wob   = (unsigned short*)(ws + 11 * MB);   // 2 MB
  unsigned short* qab   = (unsigned short*)(ws + 13 * MB);   // 8 MB
  unsigned short* kab   = (unsigned short*)(ws + 21 * MB);   // 2 MB
  unsigned short* vtb   = (unsigned short*)(ws + 23 * MB);   // 2 MB
  float*          gateA = (float*)(ws + 25 * MB);            // 64 KB
  unsigned short* vtmp  = (unsigned short*)(ws + 26 * MB);   // 2 MB
  unsigned short* yb    = xb;                                // reuse after gemm_qkv

  CvtArgs ca;
  ca.s0 = x;  ca.d0 = xb;
  ca.s1 = Wq; ca.d1 = wqkvb;
  ca.s2 = Wk; ca.d2 = wqkvb + 1024 * 1024;
  ca.s3 = Wv; ca.d3 = wqkvb + 1280 * 1024;
  ca.s4 = Wo; ca.d4 = wob;
  ca.x = x; ca.Wg = Wg; ca.gate = gateA;
  cvt_all<<<6720, 256, 0, stream>>>(ca);

  gemm_qkv<<<dim3(QKV_N / 128, (B_SZ * T_SZ) / 64), 256, 0, stream>>>(
      xb, wqkvb, ve, cosb, sinb, gateA, qab, kab, vtmp);

  v_transpose<<<256, 256, 0, stream>>>(vtmp, vtb);

  attn<<<512, 256, 0, stream>>>(qab, kab, vtb, yb);

  gemm_bt<<<dim3(C_SZ / 128, (B_SZ * T_SZ) / 64), 256, 0, stream>>>(
      yb, wob, out, C_SZ, C_SZ);
}

// Round 10
// 170.058 us; speedup vs baseline: 1.0462x; 1.0153x over previous
//
#include <hip/hip_runtime.h>
#include <stdint.h>

#define B_SZ 2
#define T_SZ 2048
#define C_SZ 1024
#define NH   16
#define NKV  4
#define HD   64
#define KVD  256
#define QKV_N 1536

typedef __attribute__((ext_vector_type(8))) short bf16x8;
typedef __attribute__((ext_vector_type(4))) float f32x4;

#define GL(p) ((const __attribute__((address_space(1))) void*)(p))
#define LD(p) ((__attribute__((address_space(3))) void*)(p))

__device__ inline unsigned short f2bf(float f) {
  union { float f; unsigned u; } v; v.f = f;
  unsigned u = v.u;
  unsigned r = (u + 0x7fffu + ((u >> 16) & 1u)) >> 16;
  return (unsigned short)r;
}
__device__ inline unsigned short bftrunc(float f) {  // truncate: 1 inst; bias cancels in O/l
  union { float f; unsigned u; } v; v.f = f;
  return (unsigned short)(v.u >> 16);
}

// ---------------- fused fp32->bf16 convert (5 segments) + gate precompute, 1 launch ----------------
struct CvtArgs {
  const float *s0, *s1, *s2, *s3, *s4;
  unsigned short *d0, *d1, *d2, *d3, *d4;
  const float *x, *Wg;
  float *gate;           // [B*T][NKV]
};
__global__ __launch_bounds__(256) void cvt_all(CvtArgs a) {
  int blk = blockIdx.x, tid = threadIdx.x;
  if (blk >= 6656) {  // gate: 3*sigmoid(x[:, :12] @ Wg^T)
    int idx = (blk - 6656) * 256 + tid;
    int bt = idx >> 2, kh = idx & 3;
    float s = 0.f;
#pragma unroll
    for (int j = 0; j < 12; j++) s += a.x[(size_t)bt * C_SZ + j] * a.Wg[kh * 12 + j];
    a.gate[idx] = 3.f / (1.f + __expf(-s));
    return;
  }
  const float* s; unsigned short* d; int i;
  if      (blk < 4096) { s = a.s0; d = a.d0; i = blk * 256 + tid; }
  else if (blk < 5120) { s = a.s1; d = a.d1; i = (blk - 4096) * 256 + tid; }
  else if (blk < 5376) { s = a.s2; d = a.d2; i = (blk - 5120) * 256 + tid; }
  else if (blk < 5632) { s = a.s3; d = a.d3; i = (blk - 5376) * 256 + tid; }
  else                 { s = a.s4; d = a.d4; i = (blk - 5632) * 256 + tid; }
  float4 f = ((const float4*)s)[i];
  ushort4 o;
  o.x = f2bf(f.x); o.y = f2bf(f.y); o.z = f2bf(f.z); o.w = f2bf(f.w);
  ((ushort4*)d)[i] = o;
}

// ========== GEMM core: 64x128 tile, BK=64, single-barrier ping-pong dbuf, XOR-swizzled LDS ==========
// Swizzle: LDS slot s (16B chunk) of row r holds global chunk s^(r&7); staging loads global
// column ((lane&7)^(lane>>3))*8 so the DMA's contiguous dest produces that layout; frag reads
// use slot (4p+quad)^(l16&7) -> 16 lanes hit 8 bank-groups 2-way = conflict-free (m136).
// Single barrier/iter: prefetch tile k+1 into buf nxt right after the barrier; the next
// barrier's vmcnt drain covers loads that had the whole compute phase in flight.
#define GEMM_PROLOG(A, Bm, K)                                                        \
  __shared__ unsigned short As[2][64 * 64];                                          \
  __shared__ unsigned short Bs[2][128 * 64];                                         \
  int tid  = threadIdx.x;                                                            \
  int lane = tid & 63;                                                               \
  int wave = tid >> 6;                                                               \
  int quad = lane >> 4;                                                              \
  int l16  = lane & 15;                                                              \
  int m0 = blockIdx.y * 64;                                                          \
  int n0 = blockIdx.x * 128;                                                         \
  int wm = (wave & 1) * 32;                                                          \
  int wn = (wave >> 1) * 64;                                                         \
  f32x4 acc[2][4];                                                                   \
  _Pragma("unroll") for (int i = 0; i < 2; i++)                                      \
    _Pragma("unroll") for (int j = 0; j < 4; j++)                                    \
      acc[i][j] = (f32x4){0.f, 0.f, 0.f, 0.f};                                       \
  int lrow = lane >> 3;                              /* 0..7 within 8-row block */   \
  int lcol = ((lane & 7) ^ lrow) * 8;                /* XOR-swizzled source chunk */ \
  int sA = wave * 16;                                                                \
  int sB = wave * 32;                                                                \
  const unsigned short* aP0 = &A[(size_t)(m0 + sA + lrow) * K + lcol];               \
  const unsigned short* aP1 = aP0 + 8 * (size_t)K;                                   \
  const unsigned short* bP0 = &Bm[(size_t)(n0 + sB + lrow) * K + lcol];              \
  const unsigned short* bP1 = bP0 + 8 * (size_t)K;                                   \
  const unsigned short* bP2 = bP0 + 16 * (size_t)K;                                  \
  const unsigned short* bP3 = bP0 + 24 * (size_t)K;                                  \
  __builtin_amdgcn_global_load_lds(GL(aP0), LD(&As[0][(sA     ) * 64]), 16, 0, 0);   \
  __builtin_amdgcn_global_load_lds(GL(aP1), LD(&As[0][(sA +  8) * 64]), 16, 0, 0);   \
  __builtin_amdgcn_global_load_lds(GL(bP0), LD(&Bs[0][(sB     ) * 64]), 16, 0, 0);   \
  __builtin_amdgcn_global_load_lds(GL(bP1), LD(&Bs[0][(sB +  8) * 64]), 16, 0, 0);   \
  __builtin_amdgcn_global_load_lds(GL(bP2), LD(&Bs[0][(sB + 16) * 64]), 16, 0, 0);   \
  __builtin_amdgcn_global_load_lds(GL(bP3), LD(&Bs[0][(sB + 24) * 64]), 16, 0, 0);   \
  int swz = l16 & 7;                                                                 \
  int nk = K >> 6;                                                                   \
  for (int ki = 0; ki < nk; ki++) {                                                  \
    int cur = ki & 1, nxt = cur ^ 1;                                                 \
    __syncthreads();                                                                 \
    if (ki + 1 < nk) {                                                               \
      int k0 = (ki + 1) << 6;                                                        \
      __builtin_amdgcn_global_load_lds(GL(aP0 + k0), LD(&As[nxt][(sA     ) * 64]), 16, 0, 0); \
      __builtin_amdgcn_global_load_lds(GL(aP1 + k0), LD(&As[nxt][(sA +  8) * 64]), 16, 0, 0); \
      __builtin_amdgcn_global_load_lds(GL(bP0 + k0), LD(&Bs[nxt][(sB     ) * 64]), 16, 0, 0); \
      __builtin_amdgcn_global_load_lds(GL(bP1 + k0), LD(&Bs[nxt][(sB +  8) * 64]), 16, 0, 0); \
      __builtin_amdgcn_global_load_lds(GL(bP2 + k0), LD(&Bs[nxt][(sB + 16) * 64]), 16, 0, 0); \
      __builtin_amdgcn_global_load_lds(GL(bP3 + k0), LD(&Bs[nxt][(sB + 24) * 64]), 16, 0, 0); \
    }                                                                                \
    _Pragma("unroll") for (int p = 0; p < 2; p++) {                                  \
      bf16x8 af[2], bfr[4];                                                          \
      _Pragma("unroll") for (int i = 0; i < 2; i++)                                  \
        af[i] = *(const bf16x8*)&As[cur][(wm + i * 16 + l16) * 64 + (((p * 4 + quad) ^ swz) * 8)]; \
      _Pragma("unroll") for (int j = 0; j < 4; j++)                                  \
        bfr[j] = *(const bf16x8*)&Bs[cur][(wn + j * 16 + l16) * 64 + (((p * 4 + quad) ^ swz) * 8)]; \
      _Pragma("unroll") for (int i = 0; i < 2; i++)                                  \
        _Pragma("unroll") for (int j = 0; j < 4; j++)                                \
          acc[i][j] = __builtin_amdgcn_mfma_f32_16x16x32_bf16(af[i], bfr[j], acc[i][j], 0, 0, 0); \
    }                                                                                \
  }

// ---------------- gemm2: C[m,n] = sum_k A[m,k]*B[n,k], fp32 out ----------------
__global__ __launch_bounds__(256) void gemm_bt(const unsigned short* __restrict__ A,
                                               const unsigned short* __restrict__ Bm,
                                               float* __restrict__ C,
                                               int N, int K) {
  GEMM_PROLOG(A, Bm, K)
#pragma unroll
  for (int i = 0; i < 2; i++) {
#pragma unroll
    for (int j = 0; j < 4; j++) {
      int col = n0 + wn + j * 16 + l16;
#pragma unroll
      for (int r = 0; r < 4; r++) {
        int row = m0 + wm + i * 16 + quad * 4 + r;
        C[(size_t)row * N + col] = acc[i][j][r];
      }
    }
  }
}

// ---------------- gemm1 fused: qkv proj + RoPE + RMSNorm + gate*ve, bf16 out ----------------
// V written COALESCED row-major (bt, kh*64+d); v_transpose produces (B,NKV,HD,T).
__global__ __launch_bounds__(256) void gemm_qkv(const unsigned short* __restrict__ A,
                                                const unsigned short* __restrict__ Bm,
                                                const float* __restrict__ ve,
                                                const float* __restrict__ cosb,
                                                const float* __restrict__ sinb,
                                                const float* __restrict__ gateArr,
                                                unsigned short* __restrict__ qa,
                                                unsigned short* __restrict__ ka,
                                                unsigned short* __restrict__ vtmp) {
  const int K = C_SZ;
  GEMM_PROLOG(A, Bm, K)

  int colbase = n0 + wn;   // multiple of 64
  if (colbase < 1280) {    // Q or K head
    int isQ = colbase < 1024;
    int h   = isQ ? (colbase >> 6) : ((colbase - 1024) >> 6);
    float scale = isQ ? (0.15f * 1.44269504088896f) : 1.2f;
    unsigned short* dst = isQ ? qa : ka;
    int nheads = isQ ? NH : NKV;
#pragma unroll
    for (int i = 0; i < 2; i++) {
#pragma unroll
      for (int r = 0; r < 4; r++) {
        int row = m0 + wm + i * 16 + quad * 4 + r;   // bt
        int t = row & (T_SZ - 1), b = row >> 11;
        float a10 = acc[i][0][r], a11 = acc[i][1][r];
        float a20 = acc[i][2][r], a21 = acc[i][3][r];
        float cv0 = cosb[t * 32 + l16],      sv0 = sinb[t * 32 + l16];
        float cv1 = cosb[t * 32 + 16 + l16], sv1 = sinb[t * 32 + 16 + l16];
        float o10 =  a10 * cv0 + a20 * sv0;
        float o11 =  a11 * cv1 + a21 * sv1;
        float o20 = -a10 * sv0 + a20 * cv0;
        float o21 = -a11 * sv1 + a21 * cv1;
        float ssq = o10 * o10 + o11 * o11 + o20 * o20 + o21 * o21;
        ssq += __shfl_xor(ssq, 1);
        ssq += __shfl_xor(ssq, 2);
        ssq += __shfl_xor(ssq, 4);
        ssq += __shfl_xor(ssq, 8);
        float rn = rsqrtf(ssq * (1.f / 64.f) + 1e-6f) * scale;
        size_t base = ((size_t)(b * nheads + h) * T_SZ + t) * HD;
        dst[base + l16]      = f2bf(o10 * rn);
        dst[base + 16 + l16] = f2bf(o11 * rn);
        dst[base + 32 + l16] = f2bf(o20 * rn);
        dst[base + 48 + l16] = f2bf(o21 * rn);
      }
    }
  } else {                 // V head: add gate*ve, write coalesced (bt, kh*64+d)
    int kh = (colbase - 1280) >> 6;
#pragma unroll
    for (int i = 0; i < 2; i++) {
#pragma unroll
      for (int r = 0; r < 4; r++) {
        int row = m0 + wm + i * 16 + quad * 4 + r;   // bt
        float g = gateArr[row * 4 + kh];
#pragma unroll
        for (int j = 0; j < 4; j++) {
          int d = j * 16 + l16;
          float val = acc[i][j][r] + g * ve[(size_t)row * KVD + kh * HD + d];
          vtmp[(size_t)row * KVD + kh * HD + d] = f2bf(val);
        }
      }
    }
  }
}

// ---------------- V transpose: (B*T, NKV*HD) -> (B,NKV,HD,T), 64x64 LDS tiles ----------------
__global__ __launch_bounds__(256) void v_transpose(const unsigned short* __restrict__ vtmp,
                                                   unsigned short* __restrict__ vt) {
  __shared__ unsigned short tile[64 * 68];
  int blk = blockIdx.x;               // b(2) x kh(4) x tb(32)
  int tb = blk & 31, kh = (blk >> 5) & 3, b = blk >> 7;
  int tid = threadIdx.x;
  int r = tid >> 2, c = (tid & 3) * 16;
  const unsigned short* src = &vtmp[((size_t)(b * T_SZ + tb * 64 + r)) * KVD + kh * HD + c];
  uint4 x0 = *(const uint4*)(src);
  uint4 x1 = *(const uint4*)(src + 8);
  *(uint2*)&tile[r * 68 + c]      = *(uint2*)&x0;
  *(uint2*)&tile[r * 68 + c + 4]  = *((uint2*)&x0 + 1);
  *(uint2*)&tile[r * 68 + c + 8]  = *(uint2*)&x1;
  *(uint2*)&tile[r * 68 + c + 12] = *((uint2*)&x1 + 1);
  __syncthreads();
  int d = tid >> 2, tc = (tid & 3) * 16;
  ushort4 o0, o1, o2, o3;
  o0.x = tile[(tc + 0) * 68 + d];  o0.y = tile[(tc + 1) * 68 + d];
  o0.z = tile[(tc + 2) * 68 + d];  o0.w = tile[(tc + 3) * 68 + d];
  o1.x = tile[(tc + 4) * 68 + d];  o1.y = tile[(tc + 5) * 68 + d];
  o1.z = tile[(tc + 6) * 68 + d];  o1.w = tile[(tc + 7) * 68 + d];
  o2.x = tile[(tc + 8) * 68 + d];  o2.y = tile[(tc + 9) * 68 + d];
  o2.z = tile[(tc + 10) * 68 + d]; o2.w = tile[(tc + 11) * 68 + d];
  o3.x = tile[(tc + 12) * 68 + d]; o3.y = tile[(tc + 13) * 68 + d];
  o3.z = tile[(tc + 14) * 68 + d]; o3.w = tile[(tc + 15) * 68 + d];
  unsigned short* dst = &vt[((size_t)(b * NKV + kh) * HD + d) * T_SZ + tb * 64 + tc];
  *(ushort4*)(dst)      = o0;
  *(ushort4*)(dst + 4)  = o1;
  *(ushort4*)(dst + 8)  = o2;
  *(ushort4*)(dst + 12) = o3;
}

// ---------------- causal flash attention: Q=128, S^T trick, single-barrier dbuf ----------------
#define KST 72
#define PST 72
__global__ __launch_bounds__(256) void attn(const unsigned short* __restrict__ qa,
                                            const unsigned short* __restrict__ ka,
                                            const unsigned short* __restrict__ vt,
                                            unsigned short* __restrict__ y) {
  // pair qt with 15-qt so co-resident blocks sum to equal work
  int bid = blockIdx.x;
  int half = bid >> 8, r = bid & 255;
  int qt = half ? (r & 15) : 15 - (r & 15);
  int bh = (half << 4) | (r >> 4);
  int b = bh >> 4, h = bh & 15;
  int kh = h >> 2;
  int tid = threadIdx.x;
  int wave = tid >> 6, lane = tid & 63;
  int quad = lane >> 4, l16 = lane & 15;

  __shared__ unsigned short Ks[2][64 * KST];   // [t_local][d]
  __shared__ unsigned short Vs[2][64 * KST];   // [d][t_local]
  __shared__ unsigned short Ps[128 * PST];     // [q_local][t_local]
  unsigned short* Pw = &Ps[(wave * 32) * PST];

  bf16x8 bq[2][2];
#pragma unroll
  for (int qi = 0; qi < 2; qi++) {
    int tq = qt * 128 + wave * 32 + qi * 16 + l16;
    const unsigned short* qp = &qa[((size_t)(b * NH + h) * T_SZ + tq) * HD];
    bq[qi][0] = *(const bf16x8*)&qp[quad * 8];
    bq[qi][1] = *(const bf16x8*)&qp[32 + quad * 8];
  }

  const unsigned short one_bf = 0x3F80;
  bf16x8 vones = {(short)one_bf, (short)one_bf, (short)one_bf, (short)one_bf,
                  (short)one_bf, (short)one_bf, (short)one_bf, (short)one_bf};

  f32x4 oacc[2][4];
  f32x4 lacc[2];
#pragma unroll
  for (int qi = 0; qi < 2; qi++) {
    lacc[qi] = (f32x4){0.f, 0.f, 0.f, 0.f};
#pragma unroll
    for (int d = 0; d < 4; d++) oacc[qi][d] = (f32x4){0.f, 0.f, 0.f, 0.f};
  }

  int lr = tid >> 2;          // 0..63
  int lc = (tid & 3) * 16;    // 0,16,32,48

  const unsigned short* kbase = &ka[(size_t)(b * NKV + kh) * T_SZ * HD];
  const unsigned short* vbase = &vt[(size_t)(b * NKV + kh) * HD * T_SZ];

  int nj = 2 * qt + 2;

  {
    const unsigned short* kp = &kbase[(size_t)lr * HD + lc];
    const unsigned short* vp = &vbase[(size_t)lr * T_SZ + lc];
    uint4 k0 = *(const uint4*)(kp);
    uint4 k1 = *(const uint4*)(kp + 8);
    uint4 v0 = *(const uint4*)(vp);
    uint4 v1 = *(const uint4*)(vp + 8);
    *(uint4*)&Ks[0][lr * KST + lc]     = k0;
    *(uint4*)&Ks[0][lr * KST + lc + 8] = k1;
    *(uint4*)&Vs[0][lr * KST + lc]     = v0;
    *(uint4*)&Vs[0][lr * KST + lc + 8] = v1;
  }

  int qrow0 = qt * 128 + wave * 32;

  for (int j = 0; j < nj; j++) {
    int cur = j & 1, nxt = cur ^ 1;
    __syncthreads();   // buf[cur] writes visible; all prior reads drained

    uint4 k0, k1, v0, v1;
    bool pf = (j + 1 < nj);
    if (pf) {
      const unsigned short* kp = &kbase[(size_t)((j + 1) * 64 + lr) * HD + lc];
      const unsigned short* vp = &vbase[(size_t)lr * T_SZ + (j + 1) * 64 + lc];
      k0 = *(const uint4*)(kp);
      k1 = *(const uint4*)(kp + 8);
      v0 = *(const uint4*)(vp);
      v1 = *(const uint4*)(vp + 8);
    }

    // S^T = K Q^T: D[m=t][n=q]; K-frags as A shared across both q-blocks
    f32x4 st[4][2];
#pragma unroll
    for (int tb = 0; tb < 4; tb++) {
      bf16x8 ak0 = *(const bf16x8*)&Ks[cur][(tb * 16 + l16) * KST + quad * 8];
      bf16x8 ak1 = *(const bf16x8*)&Ks[cur][(tb * 16 + l16) * KST + 32 + quad * 8];
#pragma unroll
      for (int qi = 0; qi < 2; qi++) {
        f32x4 s = (f32x4){0.f, 0.f, 0.f, 0.f};
        s = __builtin_amdgcn_mfma_f32_16x16x32_bf16(ak0, bq[qi][0], s, 0, 0, 0);
        s = __builtin_amdgcn_mfma_f32_16x16x32_bf16(ak1, bq[qi][1], s, 0, 0, 0);
        st[tb][qi] = s;
      }
    }

    // mask + exp2 + packed b64 store of P[q][t] (per-wave region, no barrier needed)
#pragma unroll
    for (int qi = 0; qi < 2; qi++) {
      int qlow = qrow0 + qi * 16;
      if (j * 64 + 63 > qlow) {
        int qg = qlow + l16;
#pragma unroll
        for (int tb = 0; tb < 4; tb++) {
          int tg = j * 64 + tb * 16 + quad * 4;
#pragma unroll
          for (int i = 0; i < 4; i++) {
            if (tg + i > qg) st[tb][qi][i] = -__builtin_inff();
          }
        }
      }
#pragma unroll
      for (int tb = 0; tb < 4; tb++) {
        ushort4 w;
        w.x = bftrunc(__builtin_amdgcn_exp2f(st[tb][qi][0]));
        w.y = bftrunc(__builtin_amdgcn_exp2f(st[tb][qi][1]));
        w.z = bftrunc(__builtin_amdgcn_exp2f(st[tb][qi][2]));
        w.w = bftrunc(__builtin_amdgcn_exp2f(st[tb][qi][3]));
        *(ushort4*)&Pw[(qi * 16 + l16) * PST + tb * 16 + quad * 4] = w;
      }
    }

    bf16x8 ap[2][2];
#pragma unroll
    for (int qi = 0; qi < 2; qi++) {
      ap[qi][0] = *(const bf16x8*)&Pw[(qi * 16 + l16) * PST + quad * 8];
      ap[qi][1] = *(const bf16x8*)&Pw[(qi * 16 + l16) * PST + 32 + quad * 8];
      lacc[qi] = __builtin_amdgcn_mfma_f32_16x16x32_bf16(ap[qi][0], vones, lacc[qi], 0, 0, 0);
      lacc[qi] = __builtin_amdgcn_mfma_f32_16x16x32_bf16(ap[qi][1], vones, lacc[qi], 0, 0, 0);
    }
#pragma unroll
    for (int d = 0; d < 4; d++) {
      bf16x8 bv0 = *(const bf16x8*)&Vs[cur][(d * 16 + l16) * KST + quad * 8];
      bf16x8 bv1 = *(const bf16x8*)&Vs[cur][(d * 16 + l16) * KST + 32 + quad * 8];
#pragma unroll
      for (int qi = 0; qi < 2; qi++) {
        oacc[qi][d] = __builtin_amdgcn_mfma_f32_16x16x32_bf16(ap[qi][0], bv0, oacc[qi][d], 0, 0, 0);
        oacc[qi][d] = __builtin_amdgcn_mfma_f32_16x16x32_bf16(ap[qi][1], bv1, oacc[qi][d], 0, 0, 0);
      }
    }

    if (pf) {
      *(uint4*)&Ks[nxt][lr * KST + lc]     = k0;
      *(uint4*)&Ks[nxt][lr * KST + lc + 8] = k1;
      *(uint4*)&Vs[nxt][lr * KST + lc]     = v0;
      *(uint4*)&Vs[nxt][lr * KST + lc + 8] = v1;
    }
  }

#pragma unroll
  for (int qi = 0; qi < 2; qi++) {
#pragma unroll
    for (int i = 0; i < 4; i++) {
      int tq = qrow0 + qi * 16 + quad * 4 + i;
      float inv = 1.f / lacc[qi][i];
#pragma unroll
      for (int d = 0; d < 4; d++) {
        y[((size_t)(b * T_SZ) + tq) * C_SZ + h * HD + d * 16 + l16] = f2bf(oacc[qi][d][i] * inv);
      }
    }
  }
}

extern "C" void kernel_launch(void* const* d_in, const int* in_sizes, int n_in,
                              void* d_out, int out_size, void* d_ws, size_t ws_size,
                              hipStream_t stream) {
  const float* x    = (const float*)d_in[0];
  const float* ve   = (const float*)d_in[1];
  const float* cosb = (const float*)d_in[2];
  const float* sinb = (const float*)d_in[3];
  const float* Wq   = (const float*)d_in[4];
  const float* Wk   = (const float*)d_in[5];
  const float* Wv   = (const float*)d_in[6];
  const float* Wo   = (const float*)d_in[7];
  const float* Wg   = (const float*)d_in[8];
  float* out = (float*)d_out;

  const size_t MB = 1024 * 1024;
  char* ws = (char*)d_ws;
  unsigned short* xb    = (unsigned short*)(ws);             // 8 MB (reused as yb)
  unsigned short* wqkvb = (unsigned short*)(ws + 8 * MB);    // 3 MB
  unsigned short* wob   = (unsigned short*)(ws + 11 * MB);   // 2 MB
  unsigned short* qab   = (unsigned short*)(ws + 13 * MB);   // 8 MB
  unsigned short* kab   = (unsigned short*)(ws + 21 * MB);   // 2 MB
  unsigned short* vtb   = (unsigned short*)(ws + 23 * MB);   // 2 MB
  float*          gateA = (float*)(ws + 25 * MB);            // 64 KB
  unsigned short* vtmp  = (unsigned short*)(ws + 26 * MB);   // 2 MB
  unsigned short* yb    = xb;                                // reuse after gemm_qkv

  CvtArgs ca;
  ca.s0 = x;  ca.d0 = xb;
  ca.s1 = Wq; ca.d1 = wqkvb;
  ca.s2 = Wk; ca.d2 = wqkvb + 1024 * 1024;
  ca.s3 = Wv; ca.d3 = wqkvb + 1280 * 1024;
  ca.s4 = Wo; ca.d4 = wob;
  ca.x = x; ca.Wg = Wg; ca.gate = gateA;
  cvt_all<<<6720, 256, 0, stream>>>(ca);

  gemm_qkv<<<dim3(QKV_N / 128, (B_SZ * T_SZ) / 64), 256, 0, stream>>>(
      xb, wqkvb, ve, cosb, sinb, gateA, qab, kab, vtmp);

  v_transpose<<<256, 256, 0, stream>>>(vtmp, vtb);

  attn<<<512, 256, 0, stream>>>(qab, kab, vtb, yb);

  gemm_bt<<<dim3(C_SZ / 128, (B_SZ * T_SZ) / 64), 256, 0, stream>>>(
      yb, wob, out, C_SZ, C_SZ);
}